// Round 2
// baseline (361.346 us; speedup 1.0000x reference)
//
#include <hip/hip_runtime.h>
#include <hip/hip_bf16.h>

#define B_ 64
#define L_ 2048
#define V_ 50000
#define E_ 300
#define H_ 128
#define C_ 10
#define KT 10            // k-tiles of 32 (K padded 300 -> 320)
#define WT_STRIDE 328    // bf16 elems per LDS row (bank spread, 16B-aligned rows)
#define NCHUNK 128       // 2048 / 16 steps per chunk
#define NW_CHAIN 5
#define NTHREADS 832     // 5 chain waves + 8 MFMA waves

typedef short bf16x8 __attribute__((ext_vector_type(8)));
typedef float f32x4 __attribute__((ext_vector_type(4)));

__device__ __forceinline__ unsigned enc_f32(float f) {
  unsigned u = __float_as_uint(f);
  return (u & 0x80000000u) ? ~u : (u | 0x80000000u);
}
__device__ __forceinline__ float dec_f32(unsigned u) {
  unsigned v = (u & 0x80000000u) ? (u ^ 0x80000000u) : ~u;
  return __uint_as_float(v);
}
__device__ __forceinline__ unsigned short f2bf(float f) {  // RNE f32->bf16
  unsigned u = __float_as_uint(f);
  unsigned r = 0x7FFFu + ((u >> 16) & 1u);
  return (unsigned short)((u + r) >> 16);
}

// ---- kernel 1: global min/max of emb[x] via order-preserving uint atomics ----
__global__ __launch_bounds__(256) void k_minmax(const int* __restrict__ x,
                                                const float* __restrict__ emb,
                                                unsigned* __restrict__ mm) {
  const int tid = threadIdx.x;
  float mn = 3.4e38f, mx = -3.4e38f;
  const int r0 = blockIdx.x * 64;  // 2048 blocks x 64 rows = 131072
  for (int i = 0; i < 64; ++i) {
    const int idx = x[r0 + i];
    const float* row = emb + (size_t)idx * E_;
    float v = row[tid];
    mn = fminf(mn, v); mx = fmaxf(mx, v);
    if (tid < E_ - 256) {
      float v2 = row[tid + 256];
      mn = fminf(mn, v2); mx = fmaxf(mx, v2);
    }
  }
  for (int s = 1; s < 64; s <<= 1) {
    mn = fminf(mn, __shfl_xor(mn, s));
    mx = fmaxf(mx, __shfl_xor(mx, s));
  }
  __shared__ float smn[4], smx[4];
  const int wid = tid >> 6, lane = tid & 63;
  if (lane == 0) { smn[wid] = mn; smx[wid] = mx; }
  __syncthreads();
  if (tid == 0) {
    for (int i = 1; i < 4; ++i) { mn = fminf(mn, smn[i]); mx = fmaxf(mx, smx[i]); }
    atomicMin(&mm[0], enc_f32(mn));
    atomicMax(&mm[1], enc_f32(mx));
  }
}

// ---- kernel 2: fused recurrence + MFMA matvec + max-pool (one block per b) ----
// A-tile holds bf16 RESIDUALS (w - c_t); the common path c_t is carried in f32
// and re-added in the consumer as a rank-1 f32 correction c_t * S_col.
__global__ __launch_bounds__(NTHREADS) void k_fused(
    const int* __restrict__ x, const float* __restrict__ emb,
    const float* __restrict__ alphaP, const float* __restrict__ betaP,
    const float* __restrict__ W1, const float* __restrict__ b1,
    const unsigned* __restrict__ mm, float* __restrict__ pooled) {
  __shared__ unsigned short wt[2][16][WT_STRIDE];  // double-buffered A residual tiles (bf16)
  __shared__ float cl[2][16];                      // common-path value per row (f32)
  __shared__ int xls[L_];                          // this b's token indices
  const int b = blockIdx.x;
  const int tid = threadIdx.x;
  const int wid = tid >> 6;
  const int lane = tid & 63;

  for (int i = tid; i < L_; i += NTHREADS) xls[i] = x[b * L_ + i];

  const float mn = dec_f32(mm[0]);
  const float mx = dec_f32(mm[1]);
  const float inv = 1.0f / (mx - mn);
  const float alpha = alphaP[0];
  const float beta = betaP[0];
  const float sa = -beta * inv;        // -beta*xn = sa*xe + sb
  const float sb = beta * mn * inv;    // == -beta*xn at xe=0 (~E[xn] since E[xe]~0)

  __syncthreads();

  if (wid < NW_CHAIN) {
    // ---------- producer: recurrence chains, lane ce owns embedding dim ce ----------
    const int ce = tid;                         // 0..319 (300 real, 20 pad)
    const int cec = (ce < E_) ? ce : (E_ - 1);  // clamp pad lanes (B pad rows are 0)
    float w = 1.0f;
    float cw = 1.0f;                            // deterministic common path (xe = 0)
    float pf[16];
#pragma unroll
    for (int m = 0; m < 16; ++m) {              // prefetch chunk 0 (step 0 value unused)
      const int li = (m >= 1) ? (m - 1) : 0;
      pf[m] = emb[(size_t)xls[li] * E_ + cec];
    }
    for (int c = 0; c < NCHUNK; ++c) {
      unsigned short* wrow = &wt[c & 1][0][0];
      const int cn = (c + 1 < NCHUNK) ? (c + 1) : (NCHUNK - 1);
      const int base = 16 * cn - 1;
#pragma unroll
      for (int m = 0; m < 16; ++m) {
        const float xe = pf[m];
        pf[m] = emb[(size_t)xls[base + m] * E_ + cec];  // prefetch next chunk
        if (c > 0 || m > 0) {
          w = (w + alpha * __builtin_amdgcn_rcpf(w)) + fmaf(sa, xe, sb);
          cw = (cw + alpha * __builtin_amdgcn_rcpf(cw)) + sb;
        }
        wrow[m * WT_STRIDE + ce] = f2bf(w - cw);
        if (tid == 0) cl[c & 1][m] = cw;
      }
      __syncthreads();  // pairs with consumer's top-of-loop barrier
    }
  } else {
    // ---------- consumer: MFMA over previous chunk + rank-1 c*S, running max ----------
    const int mw = wid - NW_CHAIN;      // 0..7 -> 16-col tile
    const int col = mw * 16 + (lane & 15);
    const int g = lane >> 4;
    bf16x8 bfr[KT];                     // W1^T fragments, resident all kernel
#pragma unroll
    for (int kt = 0; kt < KT; ++kt) {
      const int k0 = kt * 32 + g * 8;
#pragma unroll
      for (int i = 0; i < 8; ++i) {
        const int k = k0 + i;
        float v = 0.0f;
        if (k < E_) v = W1[k * H_ + col];
        bfr[kt][i] = (short)f2bf(v);
      }
    }
    float S = 0.0f;                     // f32 column sum of W1 for rank-1 correction
    for (int k = 0; k < E_; ++k) S += W1[k * H_ + col];

    float cm = -3.4e38f;
    const int arow = lane & 15;
    for (int c = 0; c < NCHUNK; ++c) {
      __syncthreads();  // chunk c is now complete in wt[c&1]
      const unsigned short* bp = &wt[c & 1][0][0];
      f32x4 acc = {0.0f, 0.0f, 0.0f, 0.0f};
#pragma unroll
      for (int kt = 0; kt < KT; ++kt) {
        bf16x8 a = *(const bf16x8*)(bp + arow * WT_STRIDE + kt * 32 + g * 8);
        acc = __builtin_amdgcn_mfma_f32_16x16x32_bf16(a, bfr[kt], acc, 0, 0, 0);
      }
#pragma unroll
      for (int i = 0; i < 4; ++i) {     // C/D row = (lane>>4)*4 + i
        const float z = acc[i] + cl[c & 1][g * 4 + i] * S;
        cm = fmaxf(cm, z);
      }
    }
    cm = fmaxf(cm, __shfl_xor(cm, 16));  // reduce over row-groups (all timesteps)
    cm = fmaxf(cm, __shfl_xor(cm, 32));
    if (g == 0) pooled[b * H_ + col] = tanhf(cm + b1[col]);
  }
}

// ---- kernel 3: out = tanh-pooled @ W2 + b2 ----
__global__ __launch_bounds__(640) void k_out(const float* __restrict__ pooled,
                                             const float* __restrict__ W2,
                                             const float* __restrict__ b2,
                                             float* __restrict__ out) {
  const int t = threadIdx.x;      // 640 = 64*10
  const int b = t / C_;
  const int c = t % C_;
  float s = b2[c];
#pragma unroll 8
  for (int h = 0; h < H_; ++h) s = fmaf(pooled[b * H_ + h], W2[h * C_ + c], s);
  out[t] = s;
}

extern "C" void kernel_launch(void* const* d_in, const int* in_sizes, int n_in,
                              void* d_out, int out_size, void* d_ws, size_t ws_size,
                              hipStream_t stream) {
  const int* x = (const int*)d_in[0];
  const float* emb = (const float*)d_in[1];
  const float* alpha = (const float*)d_in[2];
  const float* beta = (const float*)d_in[3];
  const float* W1 = (const float*)d_in[4];
  const float* b1 = (const float*)d_in[5];
  const float* W2 = (const float*)d_in[6];
  const float* b2 = (const float*)d_in[7];
  (void)in_sizes; (void)n_in; (void)out_size; (void)ws_size;

  unsigned* mm = (unsigned*)d_ws;                 // [0]=min enc, [1]=max enc
  float* pooled = (float*)((char*)d_ws + 64);     // 64*128 f32

  hipMemsetAsync(mm, 0xFF, 4, stream);            // min slot -> 0xFFFFFFFF
  hipMemsetAsync((char*)d_ws + 4, 0x00, 4, stream); // max slot -> 0

  k_minmax<<<2048, 256, 0, stream>>>(x, emb, mm);
  k_fused<<<B_, NTHREADS, 0, stream>>>(x, emb, alpha, beta, W1, b1, mm, pooled);
  k_out<<<1, 640, 0, stream>>>(pooled, W2, b2, (float*)d_out);
}

// Round 3
// 173.638 us; speedup vs baseline: 2.0810x; 2.0810x over previous
//
#include <hip/hip_runtime.h>
#include <hip/hip_bf16.h>

#define B_ 64
#define L_ 2048
#define V_ 50000
#define E_ 300
#define H_ 128
#define C_ 10
#define GR 64                 // emb rows per GEMM block
#define NGB ((V_ + GR - 1) / GR)   // 782

// ws layout (bytes):
//     0: mm[2] (unsigned, order-preserving encoded min/max)
//     8: bitmap[1563] words (6252 B)
//  8192: cArr[2048] f32
// 16384: pArr[2048] f32
// 24576: SArr[128] f32
// 25088: pooled[64*128] f32
// 65536: embW1 bf16 [50000][128]  (12.8 MB)

typedef short bf16x8 __attribute__((ext_vector_type(8)));
typedef float f32x4 __attribute__((ext_vector_type(4)));

__device__ __forceinline__ unsigned enc_f32(float f) {
  unsigned u = __float_as_uint(f);
  return (u & 0x80000000u) ? ~u : (u | 0x80000000u);
}
__device__ __forceinline__ float dec_f32(unsigned u) {
  unsigned v = (u & 0x80000000u) ? (u ^ 0x80000000u) : ~u;
  return __uint_as_float(v);
}
__device__ __forceinline__ unsigned short f2bf(float f) {  // RNE f32->bf16
  unsigned u = __float_as_uint(f);
  unsigned r = 0x7FFFu + ((u >> 16) & 1u);
  return (unsigned short)((u + r) >> 16);
}

// ---- K1: presence bitmap of tokens ----
__global__ __launch_bounds__(1024) void k_bitmap(const int* __restrict__ x,
                                                 unsigned* __restrict__ bm) {
  const int i = blockIdx.x * 1024 + threadIdx.x;   // grid covers exactly B_*L_
  const int v = x[i];
  atomicOr(&bm[v >> 5], 1u << (v & 31));
}

// ---- K2: embW1 = bf16(emb @ W1)  +  presence-filtered global min/max of emb ----
__global__ __launch_bounds__(512) void k_gemm(const float* __restrict__ emb,
                                              const float* __restrict__ W1,
                                              const unsigned* __restrict__ bm,
                                              unsigned* __restrict__ mm,
                                              unsigned short* __restrict__ embW1) {
  __shared__ unsigned short at[GR][328];   // bf16 A tile, 41984 B
  __shared__ float smn[8], smx[8];
  const int r0 = blockIdx.x * GR;
  const int tid = threadIdx.x;
  const int rr = tid >> 3;                 // 0..63 : row within tile (8 threads/row)
  const int c8 = tid & 7;
  const int row = r0 + rr;
  const int rowc = (row < V_) ? row : (V_ - 1);
  bool pres = ((bm[rowc >> 5] >> (rowc & 31)) & 1u) && (row < V_);
  float mn = 3.4e38f, mx = -3.4e38f;
  const float* rp = emb + (size_t)rowc * E_;
#pragma unroll
  for (int j = 0; j < 10; ++j) {
    const int k0 = c8 * 4 + 32 * j;        // multiples of 4; <=296 valid
    if (k0 < E_) {
      const float4 v = *(const float4*)(rp + k0);   // k0<=296 -> reads <=299, in-bounds
      if (pres) {
        mn = fminf(mn, fminf(fminf(v.x, v.y), fminf(v.z, v.w)));
        mx = fmaxf(mx, fmaxf(fmaxf(v.x, v.y), fmaxf(v.z, v.w)));
      }
      unsigned long long p = (unsigned long long)f2bf(v.x)
                           | ((unsigned long long)f2bf(v.y) << 16)
                           | ((unsigned long long)f2bf(v.z) << 32)
                           | ((unsigned long long)f2bf(v.w) << 48);
      *(unsigned long long*)&at[rr][k0] = p;
    } else {
      *(unsigned long long*)&at[rr][k0] = 0ull;     // zero K-pad (no NaN into MFMA)
    }
  }

  // B fragments: W1^T, col = 16*w + (lane&15), k = 32kt + 8g + i
  const int w = tid >> 6;
  const int lane = tid & 63;
  const int col = w * 16 + (lane & 15);
  const int g = lane >> 4;
  bf16x8 bfr[10];
#pragma unroll
  for (int kt = 0; kt < 10; ++kt) {
    const int k0 = kt * 32 + g * 8;
#pragma unroll
    for (int i = 0; i < 8; ++i) {
      const int k = k0 + i;
      float v = 0.0f;
      if (k < E_) v = W1[k * H_ + col];
      bfr[kt][i] = (short)f2bf(v);
    }
  }

  // block min/max reduce (writes smn/smx before the staging barrier)
#pragma unroll
  for (int s = 1; s < 64; s <<= 1) {
    mn = fminf(mn, __shfl_xor(mn, s));
    mx = fmaxf(mx, __shfl_xor(mx, s));
  }
  if (lane == 0) { smn[w] = mn; smx[w] = mx; }
  __syncthreads();
  if (tid == 0) {
    for (int i = 1; i < 8; ++i) { mn = fminf(mn, smn[i]); mx = fmaxf(mx, smx[i]); }
    atomicMin(&mm[0], enc_f32(mn));
    atomicMax(&mm[1], enc_f32(mx));
  }

  // MFMA: 4 row-tiles x 1 col-tile per wave
  f32x4 acc[4] = {{0,0,0,0},{0,0,0,0},{0,0,0,0},{0,0,0,0}};
  const int arow = lane & 15;
#pragma unroll
  for (int kt = 0; kt < 10; ++kt) {
#pragma unroll
    for (int rt = 0; rt < 4; ++rt) {
      bf16x8 a = *(const bf16x8*)&at[rt * 16 + arow][kt * 32 + g * 8];
      acc[rt] = __builtin_amdgcn_mfma_f32_16x16x32_bf16(a, bfr[kt], acc[rt], 0, 0, 0);
    }
  }
#pragma unroll
  for (int rt = 0; rt < 4; ++rt) {
#pragma unroll
    for (int i = 0; i < 4; ++i) {
      const int r = r0 + rt * 16 + g * 4 + i;     // D: row=(lane>>4)*4+i, col=lane&15
      if (r < V_) embW1[(size_t)r * H_ + col] = f2bf(acc[rt][i]);
    }
  }
}

// ---- K3: serial scalar scan for c_t, P_t  (+ S = colsum(W1) in waves 1-2) ----
__global__ __launch_bounds__(256) void k_scan(const float* __restrict__ W1,
                                              const float* __restrict__ alphaP,
                                              const float* __restrict__ betaP,
                                              const unsigned* __restrict__ mm,
                                              float* __restrict__ cArr,
                                              float* __restrict__ pArr,
                                              float* __restrict__ SArr) {
  const int tid = threadIdx.x;
  if (tid < 64) {
    const float alpha = alphaP[0];
    const float mn = dec_f32(mm[0]), mx = dec_f32(mm[1]);
    const float sb = betaP[0] * mn / (mx - mn);   // -beta*xn(xe=0)
    float c = 1.0f, P = 1.0f, rc = 1.0f, rp = 1.0f;
    const int lane = tid;
    for (int t = 0; t < L_; ++t) {
      if ((t & 63) == lane) { rc = c; rp = P; }
      const float r = __builtin_amdgcn_rcpf(c);
      const float a = fmaf(-alpha * r, r, 1.0f);  // a_t = 1 - alpha/c_t^2
      c = fmaf(alpha, r, c) + sb;
      P *= a;
      if ((t & 63) == 63) {
        cArr[(t & ~63) + lane] = rc;
        pArr[(t & ~63) + lane] = rp;
      }
    }
  } else if (tid < 192) {
    const int col = tid - 64;
    float s = 0.0f;
    for (int k = 0; k < E_; ++k) s += W1[k * H_ + col];
    SArr[col] = s;
  }
}

// ---- K4: per-b weighted prefix + max  (two-pass over 16 t-segments) ----
__global__ __launch_bounds__(1024) void k_pref(const int* __restrict__ x,
                                               const unsigned short* __restrict__ embW1,
                                               const float* __restrict__ cArr,
                                               const float* __restrict__ pArr,
                                               const float* __restrict__ SArr,
                                               const float* __restrict__ b1,
                                               const float* __restrict__ betaP,
                                               const unsigned* __restrict__ mm,
                                               float* __restrict__ pooled) {
  __shared__ int xls[L_];
  __shared__ float part[16][128];
  __shared__ float wmax[16][128];
  const int b = blockIdx.x;
  const int tid = threadIdx.x;
  const int wv = tid >> 6, lane = tid & 63;
  for (int i = tid; i < L_; i += 1024) xls[i] = x[b * L_ + i];
  const float mn = dec_f32(mm[0]), mx = dec_f32(mm[1]);
  const float binv = betaP[0] / (mx - mn);
  const int t0 = wv * 128;
  const int col2 = lane * 2;
  __syncthreads();

  // pass 1: segment partial sums of q_s * y_s
  float s0 = 0.0f, s1 = 0.0f;
#pragma unroll 4
  for (int j = 0; j < 128; ++j) {
    const int t = t0 + j;
    const unsigned y2 = *(const unsigned*)(embW1 + (size_t)xls[t] * H_ + col2);
    const float q = (t + 1 < L_) ? __builtin_amdgcn_rcpf(pArr[t + 1]) : 0.0f;
    const float y0 = __uint_as_float(y2 << 16);
    const float y1 = __uint_as_float(y2 & 0xFFFF0000u);
    s0 = fmaf(q, y0, s0);
    s1 = fmaf(q, y1, s1);
  }
  part[wv][col2] = s0; part[wv][col2 + 1] = s1;
  __syncthreads();
  float m0 = 0.0f, m1 = 0.0f;
  for (int wp = 0; wp < wv; ++wp) { m0 += part[wp][col2]; m1 += part[wp][col2 + 1]; }

  // pass 2: z_t = c_t*S - binv*P_t*m_t ; running max (m updated AFTER z)
  float z0m = -3.4e38f, z1m = -3.4e38f;
  const float S0 = SArr[col2], S1 = SArr[col2 + 1];
  float pP = pArr[t0];
#pragma unroll 4
  for (int j = 0; j < 128; ++j) {
    const int t = t0 + j;
    const unsigned y2 = *(const unsigned*)(embW1 + (size_t)xls[t] * H_ + col2);
    const float ct = cArr[t];
    const float pN = (t + 1 < L_) ? pArr[t + 1] : pArr[L_ - 1];
    const float gt = binv * pP;
    const float q = (t + 1 < L_) ? __builtin_amdgcn_rcpf(pN) : 0.0f;
    const float y0 = __uint_as_float(y2 << 16);
    const float y1 = __uint_as_float(y2 & 0xFFFF0000u);
    z0m = fmaxf(z0m, fmaf(-gt, m0, ct * S0));
    z1m = fmaxf(z1m, fmaf(-gt, m1, ct * S1));
    m0 = fmaf(q, y0, m0);
    m1 = fmaf(q, y1, m1);
    pP = pN;
  }
  wmax[wv][col2] = z0m; wmax[wv][col2 + 1] = z1m;
  __syncthreads();
  if (tid < H_) {
    float mz = wmax[0][tid];
#pragma unroll
    for (int w2 = 1; w2 < 16; ++w2) mz = fmaxf(mz, wmax[w2][tid]);
    pooled[b * H_ + tid] = tanhf(mz + b1[tid]);
  }
}

// ---- K5: out = pooled @ W2 + b2 ----
__global__ __launch_bounds__(640) void k_out(const float* __restrict__ pooled,
                                             const float* __restrict__ W2,
                                             const float* __restrict__ b2,
                                             float* __restrict__ out) {
  const int t = threadIdx.x;      // 640 = 64*10
  const int b = t / C_;
  const int c = t % C_;
  float s = b2[c];
#pragma unroll 8
  for (int h = 0; h < H_; ++h) s = fmaf(pooled[b * H_ + h], W2[h * C_ + c], s);
  out[t] = s;
}

extern "C" void kernel_launch(void* const* d_in, const int* in_sizes, int n_in,
                              void* d_out, int out_size, void* d_ws, size_t ws_size,
                              hipStream_t stream) {
  const int* x = (const int*)d_in[0];
  const float* emb = (const float*)d_in[1];
  const float* alpha = (const float*)d_in[2];
  const float* beta = (const float*)d_in[3];
  const float* W1 = (const float*)d_in[4];
  const float* b1 = (const float*)d_in[5];
  const float* W2 = (const float*)d_in[6];
  const float* b2 = (const float*)d_in[7];
  (void)in_sizes; (void)n_in; (void)out_size; (void)ws_size; (void)alpha;

  char* ws = (char*)d_ws;
  unsigned* mm = (unsigned*)ws;
  unsigned* bm = (unsigned*)(ws + 8);
  float* cArr = (float*)(ws + 8192);
  float* pArr = (float*)(ws + 16384);
  float* SArr = (float*)(ws + 24576);
  float* pooled = (float*)(ws + 25088);
  unsigned short* embW1 = (unsigned short*)(ws + 65536);

  hipMemsetAsync(mm, 0xFF, 4, stream);              // min slot -> UINT_MAX
  hipMemsetAsync(ws + 4, 0x00, 4 + 6252, stream);   // max slot + bitmap -> 0

  k_bitmap<<<(B_ * L_) / 1024, 1024, 0, stream>>>(x, bm);
  k_gemm<<<NGB, 512, 0, stream>>>(emb, W1, bm, mm, embW1);
  k_scan<<<1, 256, 0, stream>>>(W1, alpha, beta, mm, cArr, pArr, SArr);
  k_pref<<<B_, 1024, 0, stream>>>(x, embW1, cArr, pArr, SArr, b1, beta, mm, pooled);
  k_out<<<1, 640, 0, stream>>>(pooled, W2, b2, (float*)d_out);
}

// Round 4
// 123.271 us; speedup vs baseline: 2.9313x; 1.4086x over previous
//
#include <hip/hip_runtime.h>
#include <hip/hip_bf16.h>
#include <math.h>

#define B_ 64
#define L_ 2048
#define V_ 50000
#define E_ 300
#define H_ 128
#define C_ 10
#define GR 64                 // emb rows per GEMM block
#define NGB ((V_ + GR - 1) / GR)   // 782

// ws layout (bytes):
//        0: mm[2] (unsigned, order-preserving encoded min/max)
//        8: bitmap[1563] words (6252 B)
//     8192: cArr[2048] f32
//    16384: pArr[2048] f32
//    24576: SArr[128] f32
//    25088: pooled[64*128] f32
//    65536: embW1 bf16 [50000][128]   (12,800,000 B)
// 12865536: psum  f32 [64][64][128]   (2,097,152 B)
// 14962688: wmax  f32 [64][4][128]    (131,072 B)   -> needs ws >= ~15.1 MB

typedef short bf16x8 __attribute__((ext_vector_type(8)));
typedef float f32x4 __attribute__((ext_vector_type(4)));

__device__ __forceinline__ unsigned enc_f32(float f) {
  unsigned u = __float_as_uint(f);
  return (u & 0x80000000u) ? ~u : (u | 0x80000000u);
}
__device__ __forceinline__ float dec_f32(unsigned u) {
  unsigned v = (u & 0x80000000u) ? (u ^ 0x80000000u) : ~u;
  return __uint_as_float(v);
}
__device__ __forceinline__ unsigned short f2bf(float f) {  // RNE f32->bf16
  unsigned u = __float_as_uint(f);
  unsigned r = 0x7FFFu + ((u >> 16) & 1u);
  return (unsigned short)((u + r) >> 16);
}

// ---- K1: presence bitmap of tokens ----
__global__ __launch_bounds__(1024) void k_bitmap(const int* __restrict__ x,
                                                 unsigned* __restrict__ bm) {
  const int i = blockIdx.x * 1024 + threadIdx.x;   // grid covers exactly B_*L_
  const int v = x[i];
  atomicOr(&bm[v >> 5], 1u << (v & 31));
}

// ---- K2: embW1 = bf16(emb @ W1)  +  presence-filtered global min/max of emb ----
__global__ __launch_bounds__(512) void k_gemm(const float* __restrict__ emb,
                                              const float* __restrict__ W1,
                                              const unsigned* __restrict__ bm,
                                              unsigned* __restrict__ mm,
                                              unsigned short* __restrict__ embW1) {
  __shared__ unsigned short at[GR][328];   // bf16 A tile
  __shared__ float smn[8], smx[8];
  const int r0 = blockIdx.x * GR;
  const int tid = threadIdx.x;
  const int rr = tid >> 3;                 // 0..63 : row within tile (8 threads/row)
  const int c8 = tid & 7;
  const int row = r0 + rr;
  const int rowc = (row < V_) ? row : (V_ - 1);
  bool pres = ((bm[rowc >> 5] >> (rowc & 31)) & 1u) && (row < V_);
  float mn = 3.4e38f, mx = -3.4e38f;
  const float* rp = emb + (size_t)rowc * E_;
#pragma unroll
  for (int j = 0; j < 10; ++j) {
    const int k0 = c8 * 4 + 32 * j;        // multiples of 4; <=296 valid
    if (k0 < E_) {
      const float4 v = *(const float4*)(rp + k0);
      if (pres) {
        mn = fminf(mn, fminf(fminf(v.x, v.y), fminf(v.z, v.w)));
        mx = fmaxf(mx, fmaxf(fmaxf(v.x, v.y), fmaxf(v.z, v.w)));
      }
      unsigned long long p = (unsigned long long)f2bf(v.x)
                           | ((unsigned long long)f2bf(v.y) << 16)
                           | ((unsigned long long)f2bf(v.z) << 32)
                           | ((unsigned long long)f2bf(v.w) << 48);
      *(unsigned long long*)&at[rr][k0] = p;
    } else {
      *(unsigned long long*)&at[rr][k0] = 0ull;
    }
  }

  const int w = tid >> 6;
  const int lane = tid & 63;
  const int col = w * 16 + (lane & 15);
  const int g = lane >> 4;
  bf16x8 bfr[10];
#pragma unroll
  for (int kt = 0; kt < 10; ++kt) {
    const int k0 = kt * 32 + g * 8;
#pragma unroll
    for (int i = 0; i < 8; ++i) {
      const int k = k0 + i;
      float v = 0.0f;
      if (k < E_) v = W1[k * H_ + col];
      bfr[kt][i] = (short)f2bf(v);
    }
  }

#pragma unroll
  for (int s = 1; s < 64; s <<= 1) {
    mn = fminf(mn, __shfl_xor(mn, s));
    mx = fmaxf(mx, __shfl_xor(mx, s));
  }
  if (lane == 0) { smn[w] = mn; smx[w] = mx; }
  __syncthreads();
  if (tid == 0) {
    for (int i = 1; i < 8; ++i) { mn = fminf(mn, smn[i]); mx = fmaxf(mx, smx[i]); }
    atomicMin(&mm[0], enc_f32(mn));
    atomicMax(&mm[1], enc_f32(mx));
  }

  f32x4 acc[4] = {{0,0,0,0},{0,0,0,0},{0,0,0,0},{0,0,0,0}};
  const int arow = lane & 15;
#pragma unroll
  for (int kt = 0; kt < 10; ++kt) {
#pragma unroll
    for (int rt = 0; rt < 4; ++rt) {
      bf16x8 a = *(const bf16x8*)&at[rt * 16 + arow][kt * 32 + g * 8];
      acc[rt] = __builtin_amdgcn_mfma_f32_16x16x32_bf16(a, bfr[kt], acc[rt], 0, 0, 0);
    }
  }
#pragma unroll
  for (int rt = 0; rt < 4; ++rt) {
#pragma unroll
    for (int i = 0; i < 4; ++i) {
      const int r = r0 + rt * 16 + g * 4 + i;
      if (r < V_) embW1[(size_t)r * H_ + col] = f2bf(acc[rt][i]);
    }
  }
}

// ---- K3: PARALLEL scan for c_t, P_t via segment-Newton + affine shuffle-scan ----
// 64 lanes x 32 steps. Guess starts by inverting the ODE time-map, then 3
// Newton sweeps: run segment from guess tracking d = prod f'; segment map
// linearizes to affine s -> d*s + (e - d*chat); compose across lanes with a
// Hillis-Steele shuffle scan; repeat (quadratic convergence).
__global__ __launch_bounds__(192) void k_scan(const float* __restrict__ W1,
                                              const float* __restrict__ alphaP,
                                              const float* __restrict__ betaP,
                                              const unsigned* __restrict__ mm,
                                              float* __restrict__ cArr,
                                              float* __restrict__ pArr,
                                              float* __restrict__ SArr) {
  const int tid = threadIdx.x;
  if (tid < 64) {
    const int lane = tid;
    const float alpha = alphaP[0];
    const float mn = dec_f32(mm[0]), mx = dec_f32(mm[1]);
    const float sb = betaP[0] * mn / (mx - mn);   // -beta*xn(xe=0)
    const float tl = (float)(lane * 32);

    // initial guess: invert T(c) = (c-1)/sb - (alpha/sb^2) ln((a+sb c)/(a+sb))
    float c = sqrtf(fmaf(2.0f * alpha, tl, 1.0f));
    if (fabsf(sb) > 1e-7f) {
      const float isb = 1.0f / sb;
      const float k2 = alpha * isb * isb;
      const float d0 = fmaxf(alpha + sb, 1e-8f);
#pragma unroll
      for (int it = 0; it < 4; ++it) {
        const float den = fmaxf(fmaf(sb, c, alpha), 1e-8f);
        const float T = (c - 1.0f) * isb - k2 * logf(den / d0);
        c = c - (T - tl) * den / c;               // T'(c) = c/den
        c = fminf(fmaxf(c, 1.0f), 1e3f);
      }
    }
    if (lane == 0) c = 1.0f;

    // 3 Newton sweeps with affine cross-lane correction
#pragma unroll
    for (int sw = 0; sw < 3; ++sw) {
      float cc = c, d = 1.0f;
#pragma unroll
      for (int j = 0; j < 32; ++j) {
        const float r = __builtin_amdgcn_rcpf(cc);
        d *= fmaf(-alpha * r, r, 1.0f);
        cc = fmaf(alpha, r, cc) + sb;
      }
      float A = d, Bv = fmaf(-d, c, cc);          // segment map: s -> A*s + Bv
#pragma unroll
      for (int o = 1; o < 64; o <<= 1) {          // inclusive affine-compose scan
        const float A2 = __shfl_up(A, o);
        const float B2 = __shfl_up(Bv, o);
        if (lane >= o) { Bv = fmaf(A, B2, Bv); A *= A2; }
      }
      const float As = __shfl_up(A, 1);
      const float Bs = __shfl_up(Bv, 1);
      if (lane > 0) c = As + Bs;                  // start_l = C_{l-1}(1)
    }

    // final pass: emit c_t, collect a_t, then cross-lane prefix product for P_t
    float av[32];
    float cc = c, Q = 1.0f;
#pragma unroll
    for (int j = 0; j < 32; ++j) {
      cArr[lane * 32 + j] = cc;
      const float r = __builtin_amdgcn_rcpf(cc);
      const float a = fmaf(-alpha * r, r, 1.0f);
      av[j] = a; Q *= a;
      cc = fmaf(alpha, r, cc) + sb;
    }
    float Pp = Q;
#pragma unroll
    for (int o = 1; o < 64; o <<= 1) {
      const float q2 = __shfl_up(Pp, o);
      if (lane >= o) Pp *= q2;
    }
    const float Ps = __shfl_up(Pp, 1);
    float P = (lane == 0) ? 1.0f : Ps;            // P at segment start
#pragma unroll
    for (int j = 0; j < 32; ++j) {
      pArr[lane * 32 + j] = P;
      P *= av[j];
    }
  } else if (tid < 192) {
    const int col = tid - 64;
    float s = 0.0f;
    for (int k = 0; k < E_; ++k) s += W1[k * H_ + col];
    SArr[col] = s;
  }
}

// ---- K4a: per-(b, 32-step sub-segment) partial sums of q_s * y_s ----
__global__ __launch_bounds__(256) void k_psum(const int* __restrict__ x,
                                              const unsigned short* __restrict__ embW1,
                                              const float* __restrict__ pArr,
                                              float* __restrict__ psum) {
  const int bid = blockIdx.x;             // 1024 blocks
  const int b = bid >> 4, sq = bid & 15;
  const int wv = threadIdx.x >> 6, lane = threadIdx.x & 63;
  const int v = sq * 4 + wv;              // 0..63
  const int t0 = v * 32;
  const int col2 = lane * 2;
  float s0 = 0.f, s1 = 0.f;
#pragma unroll 8
  for (int j = 0; j < 32; ++j) {
    const int t = t0 + j;
    const int tok = x[b * L_ + t];
    const float q = (t + 1 < L_) ? __builtin_amdgcn_rcpf(pArr[t + 1]) : 0.0f;
    const unsigned y2 = *(const unsigned*)(embW1 + (size_t)tok * H_ + col2);
    s0 = fmaf(q, __uint_as_float(y2 << 16), s0);
    s1 = fmaf(q, __uint_as_float(y2 & 0xFFFF0000u), s1);
  }
  float* p = psum + (size_t)(b * 64 + v) * H_ + col2;
  p[0] = s0; p[1] = s1;
}

// ---- K4b: z_t = c_t*S - binv*P_t*m_t ; running max per (b, quarter) ----
__global__ __launch_bounds__(1024) void k_zmax(const int* __restrict__ x,
                                               const unsigned short* __restrict__ embW1,
                                               const float* __restrict__ cArr,
                                               const float* __restrict__ pArr,
                                               const float* __restrict__ SArr,
                                               const float* __restrict__ psum,
                                               const float* __restrict__ betaP,
                                               const unsigned* __restrict__ mm,
                                               float* __restrict__ wmax) {
  __shared__ float zsh[16][128];
  const int bid = blockIdx.x;             // 256 blocks = 1/CU
  const int b = bid >> 2, qt = bid & 3;
  const int wv = threadIdx.x >> 6, lane = threadIdx.x & 63;
  const int v = qt * 16 + wv;             // 0..63
  const int t0 = v * 32;
  const int col2 = lane * 2;
  const float mn = dec_f32(mm[0]), mx = dec_f32(mm[1]);
  const float binv = betaP[0] / (mx - mn);
  const float S0 = SArr[col2], S1 = SArr[col2 + 1];

  float m0 = 0.f, m1 = 0.f;               // prefix m at t0 from psum
  for (int u = 0; u < v; ++u) {
    const float* p = psum + (size_t)(b * 64 + u) * H_ + col2;
    m0 += p[0]; m1 += p[1];
  }
  float z0m = -3.4e38f, z1m = -3.4e38f;
#pragma unroll 4
  for (int j = 0; j < 32; ++j) {
    const int t = t0 + j;
    const int tok = x[b * L_ + t];
    const unsigned y2 = *(const unsigned*)(embW1 + (size_t)tok * H_ + col2);
    const float ct = cArr[t];
    const float gt = binv * pArr[t];
    const float q = (t + 1 < L_) ? __builtin_amdgcn_rcpf(pArr[t + 1]) : 0.0f;
    z0m = fmaxf(z0m, fmaf(-gt, m0, ct * S0));   // z uses m BEFORE adding term t
    z1m = fmaxf(z1m, fmaf(-gt, m1, ct * S1));
    m0 = fmaf(q, __uint_as_float(y2 << 16), m0);
    m1 = fmaf(q, __uint_as_float(y2 & 0xFFFF0000u), m1);
  }
  zsh[wv][col2] = z0m; zsh[wv][col2 + 1] = z1m;
  __syncthreads();
  if (threadIdx.x < 128) {
    float mz = zsh[0][threadIdx.x];
#pragma unroll
    for (int w2 = 1; w2 < 16; ++w2) mz = fmaxf(mz, zsh[w2][threadIdx.x]);
    wmax[(b * 4 + qt) * H_ + threadIdx.x] = mz;
  }
}

// ---- K4c: reduce quarters, bias + tanh -> pooled ----
__global__ __launch_bounds__(128) void k_tanh(const float* __restrict__ wmax,
                                              const float* __restrict__ b1,
                                              float* __restrict__ pooled) {
  const int b = blockIdx.x, col = threadIdx.x;
  float mz = wmax[(b * 4) * H_ + col];
#pragma unroll
  for (int qt = 1; qt < 4; ++qt) mz = fmaxf(mz, wmax[(b * 4 + qt) * H_ + col]);
  pooled[b * H_ + col] = tanhf(mz + b1[col]);
}

// ---- K5: out = pooled @ W2 + b2 ----
__global__ __launch_bounds__(640) void k_out(const float* __restrict__ pooled,
                                             const float* __restrict__ W2,
                                             const float* __restrict__ b2,
                                             float* __restrict__ out) {
  const int t = threadIdx.x;      // 640 = 64*10
  const int b = t / C_;
  const int c = t % C_;
  float s = b2[c];
#pragma unroll 8
  for (int h = 0; h < H_; ++h) s = fmaf(pooled[b * H_ + h], W2[h * C_ + c], s);
  out[t] = s;
}

extern "C" void kernel_launch(void* const* d_in, const int* in_sizes, int n_in,
                              void* d_out, int out_size, void* d_ws, size_t ws_size,
                              hipStream_t stream) {
  const int* x = (const int*)d_in[0];
  const float* emb = (const float*)d_in[1];
  const float* alpha = (const float*)d_in[2];
  const float* beta = (const float*)d_in[3];
  const float* W1 = (const float*)d_in[4];
  const float* b1 = (const float*)d_in[5];
  const float* W2 = (const float*)d_in[6];
  const float* b2 = (const float*)d_in[7];
  (void)in_sizes; (void)n_in; (void)out_size; (void)ws_size;

  char* ws = (char*)d_ws;
  unsigned* mm = (unsigned*)ws;
  unsigned* bm = (unsigned*)(ws + 8);
  float* cArr = (float*)(ws + 8192);
  float* pArr = (float*)(ws + 16384);
  float* SArr = (float*)(ws + 24576);
  float* pooled = (float*)(ws + 25088);
  unsigned short* embW1 = (unsigned short*)(ws + 65536);
  float* psum = (float*)(ws + 12865536);
  float* wmax = (float*)(ws + 14962688);

  hipMemsetAsync(mm, 0xFF, 4, stream);              // min slot -> UINT_MAX
  hipMemsetAsync(ws + 4, 0x00, 4 + 6252, stream);   // max slot + bitmap -> 0

  k_bitmap<<<(B_ * L_) / 1024, 1024, 0, stream>>>(x, bm);
  k_gemm<<<NGB, 512, 0, stream>>>(emb, W1, bm, mm, embW1);
  k_scan<<<1, 192, 0, stream>>>(W1, alpha, beta, mm, cArr, pArr, SArr);
  k_psum<<<1024, 256, 0, stream>>>(x, embW1, pArr, psum);
  k_zmax<<<256, 1024, 0, stream>>>(x, embW1, cArr, pArr, SArr, psum, beta, mm, wmax);
  k_tanh<<<64, 128, 0, stream>>>(wmax, b1, pooled);
  k_out<<<1, 640, 0, stream>>>(pooled, W2, b2, (float*)d_out);
}

// Round 5
// 117.102 us; speedup vs baseline: 3.0858x; 1.0527x over previous
//
#include <hip/hip_runtime.h>
#include <hip/hip_bf16.h>
#include <math.h>

#define B_ 64
#define L_ 2048
#define V_ 50000
#define E_ 300
#define H_ 128
#define C_ 10
#define NGB ((V_ + 63) / 64)   // 782 blocks, 64 rows each (2 subtiles of 32)

// ws layout (bytes):
//        0: mm[2] (unsigned, order-preserving encoded min/max)
//        8: bitmap[1563] words (6252 B)
//     8192: cArr[2048] f32
//    16384: pArr[2048] f32
//    24576: SArr[128] f32
//    65536: embW1 bf16 [50000][128]   (12,800,000 B)
// 12865536: psum  f32 [64][64][128]   (2,097,152 B)
// 14962688: wmax  f32 [64][4][128]    (131,072 B)   -> needs ws >= ~15.1 MB

typedef short bf16x8 __attribute__((ext_vector_type(8)));
typedef float f32x4 __attribute__((ext_vector_type(4)));

__device__ __forceinline__ unsigned enc_f32(float f) {
  unsigned u = __float_as_uint(f);
  return (u & 0x80000000u) ? ~u : (u | 0x80000000u);
}
__device__ __forceinline__ float dec_f32(unsigned u) {
  unsigned v = (u & 0x80000000u) ? (u ^ 0x80000000u) : ~u;
  return __uint_as_float(v);
}
__device__ __forceinline__ unsigned short f2bf(float f) {  // RNE f32->bf16
  unsigned u = __float_as_uint(f);
  unsigned r = 0x7FFFu + ((u >> 16) & 1u);
  return (unsigned short)((u + r) >> 16);
}

// ---- K0: init mm + zero bitmap (replaces 2 hipMemsetAsync dispatches) ----
__global__ __launch_bounds__(512) void k_init(unsigned* __restrict__ mm,
                                              unsigned* __restrict__ bm) {
  const int t = threadIdx.x;
  if (t == 0) { mm[0] = 0xFFFFFFFFu; mm[1] = 0u; }
  for (int i = t; i < 1563; i += 512) bm[i] = 0u;
}

// ---- K1: presence bitmap of tokens ----
__global__ __launch_bounds__(1024) void k_bitmap(const int* __restrict__ x,
                                                 unsigned* __restrict__ bm) {
  const int i = blockIdx.x * 1024 + threadIdx.x;   // grid covers exactly B_*L_
  const int v = x[i];
  atomicOr(&bm[v >> 5], 1u << (v & 31));
}

// ---- K2: embW1 = bf16(emb @ W1) + presence-filtered min/max ----
// 64 rows/block as 2 subtiles of 32, async-stage split: subtile st+1's global
// loads are issued before subtile st's MFMA so HBM latency hides under compute.
// MFMA operands swapped (A=W1 frags, B=emb rows) so D's fast index is H ->
// each lane stores 4 consecutive bf16 (8 B) of embW1.
__global__ __launch_bounds__(512) void k_gemm(const float* __restrict__ emb,
                                              const float* __restrict__ W1,
                                              const unsigned* __restrict__ bm,
                                              unsigned* __restrict__ mm,
                                              unsigned short* __restrict__ embW1) {
  __shared__ unsigned short at[32][328];   // bf16 subtile, 20,992 B
  __shared__ float smn[8], smx[8];
  const int r0 = blockIdx.x * 64;
  const int tid = threadIdx.x;
  const int w = tid >> 6;
  const int lane = tid & 63;
  const int arow = lane & 15;
  const int g = lane >> 4;
  // staging map: thread -> row rr = tid>>4 (0..31), c16 = tid&15, 5 float4 each
  const int rr = tid >> 4;
  const int c16 = tid & 15;

  float mn = 3.4e38f, mx = -3.4e38f;

  // ---- issue subtile-0 loads ----
  float4 pf[5];
  {
    const int row = r0 + rr;
    const float* rp = emb + (size_t)((row < V_) ? row : (V_ - 1)) * E_;
#pragma unroll
    for (int j = 0; j < 5; ++j) {
      const int k0 = c16 * 4 + 64 * j;
      pf[j] = (k0 < E_) ? *(const float4*)(rp + k0) : float4{0, 0, 0, 0};
    }
  }

  // ---- B... now A-fragments: W1^T, m-dim = col, k = 32kt+8g+i (L2-resident) ----
  bf16x8 bfr[10];
  const int col = w * 16 + arow;
#pragma unroll
  for (int kt = 0; kt < 10; ++kt) {
    const int k0 = kt * 32 + g * 8;
#pragma unroll
    for (int i = 0; i < 8; ++i) {
      const int k = k0 + i;
      bfr[kt][i] = (short)((k < E_) ? f2bf(W1[k * H_ + col]) : 0);
    }
  }

#pragma unroll
  for (int st = 0; st < 2; ++st) {
    const int row = r0 + st * 32 + rr;
    const bool pres = (row < V_) && ((bm[row >> 5] >> (row & 31)) & 1u);
    // convert staged regs -> LDS (+ min/max on present rows)
#pragma unroll
    for (int j = 0; j < 5; ++j) {
      const int k0 = c16 * 4 + 64 * j;
      if (k0 < 320) {
        const float4 v = pf[j];
        if (pres && k0 < E_) {
          mn = fminf(mn, fminf(fminf(v.x, v.y), fminf(v.z, v.w)));
          mx = fmaxf(mx, fmaxf(fmaxf(v.x, v.y), fmaxf(v.z, v.w)));
        }
        unsigned long long p = 0ull;
        if (k0 < E_)
          p = (unsigned long long)f2bf(v.x) | ((unsigned long long)f2bf(v.y) << 16)
            | ((unsigned long long)f2bf(v.z) << 32) | ((unsigned long long)f2bf(v.w) << 48);
        *(unsigned long long*)&at[rr][k0] = p;
      }
    }
    // issue subtile-1 loads NOW (hide under barrier + MFMA below)
    if (st == 0) {
      const int row1 = r0 + 32 + rr;
      const float* rp = emb + (size_t)((row1 < V_) ? row1 : (V_ - 1)) * E_;
#pragma unroll
      for (int j = 0; j < 5; ++j) {
        const int k0 = c16 * 4 + 64 * j;
        pf[j] = (k0 < E_) ? *(const float4*)(rp + k0) : float4{0, 0, 0, 0};
      }
    }
    __syncthreads();   // subtile st staged
    // MFMA: 2 row-tiles x 10 kt; D row = h-offset, D col = emb row
#pragma unroll
    for (int rt = 0; rt < 2; ++rt) {
      f32x4 acc = {0, 0, 0, 0};
#pragma unroll
      for (int kt = 0; kt < 10; ++kt) {
        bf16x8 bb = *(const bf16x8*)&at[rt * 16 + arow][kt * 32 + g * 8];
        acc = __builtin_amdgcn_mfma_f32_16x16x32_bf16(bfr[kt], bb, acc, 0, 0, 0);
      }
      const int grow = r0 + st * 32 + rt * 16 + arow;
      if (grow < V_) {
        unsigned long long p = (unsigned long long)f2bf(acc[0])
                             | ((unsigned long long)f2bf(acc[1]) << 16)
                             | ((unsigned long long)f2bf(acc[2]) << 32)
                             | ((unsigned long long)f2bf(acc[3]) << 48);
        *(unsigned long long*)&embW1[(size_t)grow * H_ + w * 16 + g * 4] = p;
      }
    }
    __syncthreads();   // all reads of subtile st done before re-staging LDS
  }

  // ---- block min/max reduce -> global atomics ----
#pragma unroll
  for (int s = 1; s < 64; s <<= 1) {
    mn = fminf(mn, __shfl_xor(mn, s));
    mx = fmaxf(mx, __shfl_xor(mx, s));
  }
  if (lane == 0) { smn[w] = mn; smx[w] = mx; }
  __syncthreads();
  if (tid == 0) {
#pragma unroll
    for (int i = 1; i < 8; ++i) { mn = fminf(mn, smn[i]); mx = fmaxf(mx, smx[i]); }
    atomicMin(&mm[0], enc_f32(mn));
    atomicMax(&mm[1], enc_f32(mx));
  }
}

// ---- K3: PARALLEL scan for c_t, P_t (segment-Newton + affine shuffle-scan) ----
__global__ __launch_bounds__(192) void k_scan(const float* __restrict__ W1,
                                              const float* __restrict__ alphaP,
                                              const float* __restrict__ betaP,
                                              const unsigned* __restrict__ mm,
                                              float* __restrict__ cArr,
                                              float* __restrict__ pArr,
                                              float* __restrict__ SArr) {
  const int tid = threadIdx.x;
  if (tid < 64) {
    const int lane = tid;
    const float alpha = alphaP[0];
    const float mn = dec_f32(mm[0]), mx = dec_f32(mm[1]);
    const float sb = betaP[0] * mn / (mx - mn);   // -beta*xn(xe=0)
    const float tl = (float)(lane * 32);

    float c = sqrtf(fmaf(2.0f * alpha, tl, 1.0f));
    if (fabsf(sb) > 1e-7f) {
      const float isb = 1.0f / sb;
      const float k2 = alpha * isb * isb;
      const float d0 = fmaxf(alpha + sb, 1e-8f);
#pragma unroll
      for (int it = 0; it < 4; ++it) {
        const float den = fmaxf(fmaf(sb, c, alpha), 1e-8f);
        const float T = (c - 1.0f) * isb - k2 * logf(den / d0);
        c = c - (T - tl) * den / c;
        c = fminf(fmaxf(c, 1.0f), 1e3f);
      }
    }
    if (lane == 0) c = 1.0f;

#pragma unroll
    for (int sw = 0; sw < 3; ++sw) {
      float cc = c, d = 1.0f;
#pragma unroll
      for (int j = 0; j < 32; ++j) {
        const float r = __builtin_amdgcn_rcpf(cc);
        d *= fmaf(-alpha * r, r, 1.0f);
        cc = fmaf(alpha, r, cc) + sb;
      }
      float A = d, Bv = fmaf(-d, c, cc);
#pragma unroll
      for (int o = 1; o < 64; o <<= 1) {
        const float A2 = __shfl_up(A, o);
        const float B2 = __shfl_up(Bv, o);
        if (lane >= o) { Bv = fmaf(A, B2, Bv); A *= A2; }
      }
      const float As = __shfl_up(A, 1);
      const float Bs = __shfl_up(Bv, 1);
      if (lane > 0) c = As + Bs;
    }

    float av[32];
    float cc = c, Q = 1.0f;
#pragma unroll
    for (int j = 0; j < 32; ++j) {
      cArr[lane * 32 + j] = cc;
      const float r = __builtin_amdgcn_rcpf(cc);
      const float a = fmaf(-alpha * r, r, 1.0f);
      av[j] = a; Q *= a;
      cc = fmaf(alpha, r, cc) + sb;
    }
    float Pp = Q;
#pragma unroll
    for (int o = 1; o < 64; o <<= 1) {
      const float q2 = __shfl_up(Pp, o);
      if (lane >= o) Pp *= q2;
    }
    const float Ps = __shfl_up(Pp, 1);
    float P = (lane == 0) ? 1.0f : Ps;
#pragma unroll
    for (int j = 0; j < 32; ++j) {
      pArr[lane * 32 + j] = P;
      P *= av[j];
    }
  } else if (tid < 192) {
    const int col = tid - 64;
    float s = 0.0f;
    for (int k = 0; k < E_; ++k) s += W1[k * H_ + col];
    SArr[col] = s;
  }
}

// ---- K4a: per-(b, 32-step sub-segment) partial sums of q_s * y_s ----
__global__ __launch_bounds__(256) void k_psum(const int* __restrict__ x,
                                              const unsigned short* __restrict__ embW1,
                                              const float* __restrict__ pArr,
                                              float* __restrict__ psum) {
  const int bid = blockIdx.x;             // 1024 blocks
  const int b = bid >> 4, sq = bid & 15;
  const int wv = threadIdx.x >> 6, lane = threadIdx.x & 63;
  const int v = sq * 4 + wv;              // 0..63
  const int t0 = v * 32;
  const int col2 = lane * 2;
  float s0 = 0.f, s1 = 0.f;
#pragma unroll 8
  for (int j = 0; j < 32; ++j) {
    const int t = t0 + j;
    const int tok = x[b * L_ + t];
    const float q = (t + 1 < L_) ? __builtin_amdgcn_rcpf(pArr[t + 1]) : 0.0f;
    const unsigned y2 = *(const unsigned*)(embW1 + (size_t)tok * H_ + col2);
    s0 = fmaf(q, __uint_as_float(y2 << 16), s0);
    s1 = fmaf(q, __uint_as_float(y2 & 0xFFFF0000u), s1);
  }
  float* p = psum + (size_t)(b * 64 + v) * H_ + col2;
  p[0] = s0; p[1] = s1;
}

// ---- K4b: z_t = c_t*S - binv*P_t*m_t ; running max per (b, quarter) ----
__global__ __launch_bounds__(1024) void k_zmax(const int* __restrict__ x,
                                               const unsigned short* __restrict__ embW1,
                                               const float* __restrict__ cArr,
                                               const float* __restrict__ pArr,
                                               const float* __restrict__ SArr,
                                               const float* __restrict__ psum,
                                               const float* __restrict__ betaP,
                                               const unsigned* __restrict__ mm,
                                               float* __restrict__ wmax) {
  __shared__ float zsh[16][128];
  const int bid = blockIdx.x;             // 256 blocks
  const int b = bid >> 2, qt = bid & 3;
  const int wv = threadIdx.x >> 6, lane = threadIdx.x & 63;
  const int v = qt * 16 + wv;             // 0..63
  const int t0 = v * 32;
  const int col2 = lane * 2;
  const float mn = dec_f32(mm[0]), mx = dec_f32(mm[1]);
  const float binv = betaP[0] / (mx - mn);
  const float S0 = SArr[col2], S1 = SArr[col2 + 1];

  float m0 = 0.f, m1 = 0.f;               // prefix m at t0 from psum
  for (int u = 0; u < v; ++u) {
    const float* p = psum + (size_t)(b * 64 + u) * H_ + col2;
    m0 += p[0]; m1 += p[1];
  }
  float z0m = -3.4e38f, z1m = -3.4e38f;
#pragma unroll 4
  for (int j = 0; j < 32; ++j) {
    const int t = t0 + j;
    const int tok = x[b * L_ + t];
    const unsigned y2 = *(const unsigned*)(embW1 + (size_t)tok * H_ + col2);
    const float ct = cArr[t];
    const float gt = binv * pArr[t];
    const float q = (t + 1 < L_) ? __builtin_amdgcn_rcpf(pArr[t + 1]) : 0.0f;
    z0m = fmaxf(z0m, fmaf(-gt, m0, ct * S0));   // z uses m BEFORE adding term t
    z1m = fmaxf(z1m, fmaf(-gt, m1, ct * S1));
    m0 = fmaf(q, __uint_as_float(y2 << 16), m0);
    m1 = fmaf(q, __uint_as_float(y2 & 0xFFFF0000u), m1);
  }
  zsh[wv][col2] = z0m; zsh[wv][col2 + 1] = z1m;
  __syncthreads();
  if (threadIdx.x < 128) {
    float mz = zsh[0][threadIdx.x];
#pragma unroll
    for (int w2 = 1; w2 < 16; ++w2) mz = fmaxf(mz, zsh[w2][threadIdx.x]);
    wmax[(b * 4 + qt) * H_ + threadIdx.x] = mz;
  }
}

// ---- K5: fused quarter-max + tanh + (pooled @ W2 + b2) ----
__global__ __launch_bounds__(128) void k_out(const float* __restrict__ wmax,
                                             const float* __restrict__ b1,
                                             const float* __restrict__ W2,
                                             const float* __restrict__ b2,
                                             float* __restrict__ out) {
  __shared__ float sh[128];
  const int b = blockIdx.x, h = threadIdx.x;
  float mz = wmax[(b * 4) * H_ + h];
#pragma unroll
  for (int qt = 1; qt < 4; ++qt) mz = fmaxf(mz, wmax[(b * 4 + qt) * H_ + h]);
  sh[h] = tanhf(mz + b1[h]);
  __syncthreads();
  if (h < C_) {
    float s = b2[h];
#pragma unroll 8
    for (int k = 0; k < H_; ++k) s = fmaf(sh[k], W2[k * C_ + h], s);
    out[b * C_ + h] = s;
  }
}

extern "C" void kernel_launch(void* const* d_in, const int* in_sizes, int n_in,
                              void* d_out, int out_size, void* d_ws, size_t ws_size,
                              hipStream_t stream) {
  const int* x = (const int*)d_in[0];
  const float* emb = (const float*)d_in[1];
  const float* alpha = (const float*)d_in[2];
  const float* beta = (const float*)d_in[3];
  const float* W1 = (const float*)d_in[4];
  const float* b1 = (const float*)d_in[5];
  const float* W2 = (const float*)d_in[6];
  const float* b2 = (const float*)d_in[7];
  (void)in_sizes; (void)n_in; (void)out_size; (void)ws_size;

  char* ws = (char*)d_ws;
  unsigned* mm = (unsigned*)ws;
  unsigned* bm = (unsigned*)(ws + 8);
  float* cArr = (float*)(ws + 8192);
  float* pArr = (float*)(ws + 16384);
  float* SArr = (float*)(ws + 24576);
  unsigned short* embW1 = (unsigned short*)(ws + 65536);
  float* psum = (float*)(ws + 12865536);
  float* wmax = (float*)(ws + 14962688);

  k_init<<<1, 512, 0, stream>>>(mm, bm);
  k_bitmap<<<(B_ * L_) / 1024, 1024, 0, stream>>>(x, bm);
  k_gemm<<<NGB, 512, 0, stream>>>(emb, W1, bm, mm, embW1);
  k_scan<<<1, 192, 0, stream>>>(W1, alpha, beta, mm, cArr, pArr, SArr);
  k_psum<<<1024, 256, 0, stream>>>(x, embW1, pArr, psum);
  k_zmax<<<256, 1024, 0, stream>>>(x, embW1, cArr, pArr, SArr, psum, beta, mm, wmax);
  k_out<<<64, 128, 0, stream>>>(wmax, b1, W2, b2, (float*)d_out);
}